// Round 3
// baseline (690.221 us; speedup 1.0000x reference)
//
#include <hip/hip_runtime.h>
#include <hip/hip_bf16.h>
#include <stdint.h>

// Problem constants
#define NB    128   // batches
#define TT    64    // tokens per batch (M per batch)
#define KTOT  1024  // K for both layers (D_IN and D_HID are both 1024)
#define DHID  1024
#define DOUT  1536
#define NCAT  32

#define BK    64    // K tile
#define TN    128   // N tile

typedef unsigned short u16;
typedef __attribute__((ext_vector_type(8))) short bf16x8;
typedef __attribute__((ext_vector_type(4))) float f32x4;
typedef __attribute__((ext_vector_type(4))) unsigned int uint4v;
typedef __attribute__((ext_vector_type(4))) float float4v;

__device__ __forceinline__ float bf2f(u16 u) {
    unsigned int x = ((unsigned int)u) << 16;
    return __builtin_bit_cast(float, x);
}
__device__ __forceinline__ unsigned int f2bf_u32(float f) {
    unsigned int x = __builtin_bit_cast(unsigned int, f);
    return (x + 0x7FFFu + ((x >> 16) & 1u)) >> 16;  // RNE
}
__device__ __forceinline__ u16 f2bf(float f) { return (u16)f2bf_u32(f); }

// Runtime dtype flag: 1 if float tensors are fp32, 0 if bf16 (proven working r2).
__device__ int g_is_f32;

__global__ void detect_dtype(const unsigned int* __restrict__ xw) {
    if (threadIdx.x == 0 && blockIdx.x == 0) {
        int hits = 0;
        for (int i = 0; i < 256; ++i) {
            unsigned int e = (xw[i] >> 7) & 0xFF;
            hits += (e >= 120 && e <= 132) ? 1 : 0;
        }
        g_is_f32 = (hits < 128) ? 1 : 0;
    }
}

// ---------------------------------------------------------------------------
// One-time W transpose: W[cat][k][n] (row-major, dynamic dtype) ->
// WT[cat][n][k] (bf16, k-contiguous). Block = 256 threads: n-tile 256, k-tile
// 64. Thread: fixed n, gathers 64 k's (coalesced across lanes per k), emits
// 8x b128 stores.
// ---------------------------------------------------------------------------
template<int NW>
__global__ __launch_bounds__(256)
void transpose_w(const void* __restrict__ Win, u16* __restrict__ WT)
{
    constexpr int NBLK = NW / 256;          // n-blocks per (cat,kb)
    const bool f32 = (g_is_f32 != 0);
    const int cat  = blockIdx.x / (16 * NBLK);
    const int rem  = blockIdx.x % (16 * NBLK);
    const int kb   = rem / NBLK;
    const int nb   = rem % NBLK;

    const int n  = nb * 256 + threadIdx.x;
    const int k0 = kb * 64;

    const size_t srcOff = (size_t)cat * ((size_t)KTOT * NW);
    const u16*   s16 = (const u16*)Win + srcOff;
    const float* s32 = (const float*)Win + srcOff;
    u16* dst = WT + ((size_t)cat * NW + n) * KTOT + k0;

#pragma unroll
    for (int j = 0; j < 8; ++j) {
        unsigned int s[8];
        if (!f32) {
#pragma unroll
            for (int i = 0; i < 8; ++i)
                s[i] = s16[(size_t)(k0 + j * 8 + i) * NW + n];
        } else {
#pragma unroll
            for (int i = 0; i < 8; ++i)
                s[i] = f2bf_u32(s32[(size_t)(k0 + j * 8 + i) * NW + n]);
        }
        uint4v v;
        v.x = s[0] | (s[1] << 16);
        v.y = s[2] | (s[3] << 16);
        v.z = s[4] | (s[5] << 16);
        v.w = s[6] | (s[7] << 16);
        *(uint4v*)(dst + j * 8) = v;
    }
}

// ---------------------------------------------------------------------------
// Fast GEMM: C[b] = act(A[b] (64xK) @ W[cat[b]] + bias), W from WT (n-major,
// k-contig bf16). XOR-swizzled LDS (16B chunk c of row r at position c^(r&7))
// -> conflict-free b128 reads AND a lane-linear layout compatible with
// global_load_lds (swizzle applied on the gather side).
// ---------------------------------------------------------------------------
template<int NW, bool RELU, bool A_DYN, bool OUT_DYN>
__global__ __launch_bounds__(256, 4)
void gemm_fast(const void* __restrict__ Ain,
               const u16* __restrict__ WT,
               const void* __restrict__ BiasIn,
               void* __restrict__ Cout,
               const int* __restrict__ cat_ids)
{
    constexpr int NT = NW / TN;
    __shared__ u16 As[TT * BK];    // 8 KiB
    __shared__ u16 Ws[TN * BK];    // 16 KiB

    const bool f32  = (g_is_f32 != 0);
    const bool aF32 = A_DYN && f32;
    const bool oF32 = OUT_DYN && f32;

    const int b   = blockIdx.x / NT;
    const int nt  = blockIdx.x % NT;
    const int cat = cat_ids[b];

    const int tid  = threadIdx.x;
    const int lane = tid & 63;
    const int l16  = lane & 15;
    const int q    = lane >> 4;      // quad 0..3
    const int wave = tid >> 6;
    const int wm   = wave & 1;       // m half: rows wm*32..+31
    const int wn   = wave >> 1;      // n half: cols wn*64..+63

    const size_t aOff = (size_t)b * (TT * KTOT);
    const u16*   Ab16 = (const u16*)Ain + aOff;
    const float* Ab32 = (const float*)Ain + aOff;
    // WT expert slab, n-rows for this n-tile
    const u16* Wt = WT + (size_t)cat * ((size_t)NW * KTOT) + (size_t)(nt * TN) * KTOT;

    // A staging map: thread -> row ar, chunk pair c0,c0+1 (16B chunks of 8 elems)
    const int ar = tid >> 2;             // 0..63
    const int c0 = (tid & 3) * 2;        // 0,2,4,6
    const int p0 = c0 ^ (ar & 7);
    const int p1 = (c0 + 1) ^ (ar & 7);
    // W staging map (global_load_lds): lane -> sub-row, swizzled source chunk
    const int lrow = lane >> 3;                 // 0..7
    const int lc   = (lane & 7) ^ lrow;         // source chunk for this slot

    f32x4 acc[2][4];
#pragma unroll
    for (int im = 0; im < 2; ++im)
#pragma unroll
        for (int in = 0; in < 4; ++in)
            acc[im][in] = (f32x4){0.f, 0.f, 0.f, 0.f};

    for (int kk = 0; kk < KTOT; kk += BK) {
        // ---- stage W via async global->LDS, 4 rounds of 1 KiB per wave ----
#pragma unroll
        for (int j = 0; j < 4; ++j) {
            const int row = wave * 32 + j * 8 + lrow;          // n row 0..127
            const u16* g = Wt + (size_t)row * KTOT + kk + lc * 8;
            __builtin_amdgcn_global_load_lds(
                (const __attribute__((address_space(1))) void*)g,
                (__attribute__((address_space(3))) void*)&Ws[(wave * 4 + j) * 512],
                16, 0, 0);
        }
        // ---- stage A (manual, handles fp32 conversion), swizzled ----
        if (!aF32) {
            const u16* src = Ab16 + ar * KTOT + kk + c0 * 8;
            uint4v v0 = *(const uint4v*)(src);
            uint4v v1 = *(const uint4v*)(src + 8);
            *(uint4v*)&As[ar * BK + p0 * 8] = v0;
            *(uint4v*)&As[ar * BK + p1 * 8] = v1;
        } else {
            const float* src = Ab32 + ar * KTOT + kk + c0 * 8;
            float4v f0 = *(const float4v*)(src);
            float4v f1 = *(const float4v*)(src + 4);
            float4v f2 = *(const float4v*)(src + 8);
            float4v f3 = *(const float4v*)(src + 12);
            uint4v v0, v1;
            v0.x = f2bf_u32(f0.x) | (f2bf_u32(f0.y) << 16);
            v0.y = f2bf_u32(f0.z) | (f2bf_u32(f0.w) << 16);
            v0.z = f2bf_u32(f1.x) | (f2bf_u32(f1.y) << 16);
            v0.w = f2bf_u32(f1.z) | (f2bf_u32(f1.w) << 16);
            v1.x = f2bf_u32(f2.x) | (f2bf_u32(f2.y) << 16);
            v1.y = f2bf_u32(f2.z) | (f2bf_u32(f2.w) << 16);
            v1.z = f2bf_u32(f3.x) | (f2bf_u32(f3.y) << 16);
            v1.w = f2bf_u32(f3.z) | (f2bf_u32(f3.w) << 16);
            *(uint4v*)&As[ar * BK + p0 * 8] = v0;
            *(uint4v*)&As[ar * BK + p1 * 8] = v1;
        }
        __syncthreads();   // drains vmcnt (global_load_lds) + lgkmcnt

        // ---- MFMA: 2 k-steps of 32 ----
#pragma unroll
        for (int s = 0; s < 2; ++s) {
            const int c = s * 4 + q;            // 16B chunk index along k
            bf16x8 a[2], bb[4];
#pragma unroll
            for (int im = 0; im < 2; ++im) {
                const int r = wm * 32 + im * 16 + l16;
                a[im] = *(const bf16x8*)&As[r * BK + (c ^ (l16 & 7)) * 8];
            }
#pragma unroll
            for (int in = 0; in < 4; ++in) {
                const int r = wn * 64 + in * 16 + l16;
                bb[in] = *(const bf16x8*)&Ws[r * BK + (c ^ (l16 & 7)) * 8];
            }
#pragma unroll
            for (int im = 0; im < 2; ++im)
#pragma unroll
                for (int in = 0; in < 4; ++in)
                    acc[im][in] = __builtin_amdgcn_mfma_f32_16x16x32_bf16(
                        a[im], bb[in], acc[im][in], 0, 0, 0);
        }
        __syncthreads();
    }

    // ---- epilogue: bias (+ReLU), store. C/D map: col=lane&15, row=q*4+reg ----
    const u16*   bias16 = (const u16*)BiasIn + (size_t)cat * NW + nt * TN;
    const float* bias32 = (const float*)BiasIn + (size_t)cat * NW + nt * TN;
    const size_t cOff = (size_t)b * TT * NW + (size_t)nt * TN;
    u16*   C16 = (u16*)Cout + cOff;
    float* C32 = (float*)Cout + cOff;
#pragma unroll
    for (int in = 0; in < 4; ++in) {
        const int ncol = wn * 64 + in * 16 + l16;
        const float bv = f32 ? bias32[ncol] : bf2f(bias16[ncol]);
#pragma unroll
        for (int im = 0; im < 2; ++im) {
#pragma unroll
            for (int r = 0; r < 4; ++r) {
                const int m = wm * 32 + im * 16 + q * 4 + r;
                float v = acc[im][in][r] + bv;
                if (RELU) v = fmaxf(v, 0.f);
                if (oF32) C32[(size_t)m * NW + ncol] = v;
                else      C16[(size_t)m * NW + ncol] = f2bf(v);
            }
        }
    }
}

// ---------------------------------------------------------------------------
// Fallback GEMM (round-2, proven): per-use scalar W gather. Used only if
// ws_size can't hold the transposed weights.
// ---------------------------------------------------------------------------
#define PADR  72
template<int NW, bool RELU, bool A_DYN, bool OUT_DYN>
__global__ __launch_bounds__(256, 4)
void gemm_cat_v2(const void* __restrict__ Ain,
                 const void* __restrict__ Win,
                 const void* __restrict__ BiasIn,
                 void* __restrict__ Cout,
                 const int* __restrict__ cat_ids)
{
    constexpr int NT = NW / TN;
    __shared__ u16 As[TT * PADR];
    __shared__ u16 Bs[TN * PADR];

    const bool f32  = (g_is_f32 != 0);
    const bool aF32 = A_DYN && f32;
    const bool oF32 = OUT_DYN && f32;

    const int b   = blockIdx.x / NT;
    const int nt  = blockIdx.x % NT;
    const int cat = cat_ids[b];

    const int tid  = threadIdx.x;
    const int lane = tid & 63;
    const int l16  = lane & 15;
    const int q    = lane >> 4;
    const int wave = tid >> 6;
    const int wm   = wave & 1;
    const int wn   = wave >> 1;

    const size_t aOff = (size_t)b * (TT * KTOT);
    const u16*   Ab16 = (const u16*)Ain + aOff;
    const float* Ab32 = (const float*)Ain + aOff;
    const size_t wOff = (size_t)cat * ((size_t)KTOT * NW) + (size_t)nt * TN;
    const u16*   Wb16 = (const u16*)Win + wOff;
    const float* Wb32 = (const float*)Win + wOff;

    const int ar = tid >> 2;
    const int ac = (tid & 3) * 16;
    const int bn  = tid & 127;
    const int bk0 = tid >> 7;

    f32x4 acc[2][4];
#pragma unroll
    for (int im = 0; im < 2; ++im)
#pragma unroll
        for (int in = 0; in < 4; ++in)
            acc[im][in] = (f32x4){0.f, 0.f, 0.f, 0.f};

    for (int kk = 0; kk < KTOT; kk += BK) {
        if (!aF32) {
            const u16* src = Ab16 + ar * KTOT + kk + ac;
            uint4v v0 = *(const uint4v*)(src);
            uint4v v1 = *(const uint4v*)(src + 8);
            *(uint4v*)&As[ar * PADR + ac]     = v0;
            *(uint4v*)&As[ar * PADR + ac + 8] = v1;
        } else {
            const float* src = Ab32 + ar * KTOT + kk + ac;
            float4v f0 = *(const float4v*)(src);
            float4v f1 = *(const float4v*)(src + 4);
            float4v f2 = *(const float4v*)(src + 8);
            float4v f3 = *(const float4v*)(src + 12);
            uint4v v0, v1;
            v0.x = f2bf_u32(f0.x) | (f2bf_u32(f0.y) << 16);
            v0.y = f2bf_u32(f0.z) | (f2bf_u32(f0.w) << 16);
            v0.z = f2bf_u32(f1.x) | (f2bf_u32(f1.y) << 16);
            v0.w = f2bf_u32(f1.z) | (f2bf_u32(f1.w) << 16);
            v1.x = f2bf_u32(f2.x) | (f2bf_u32(f2.y) << 16);
            v1.y = f2bf_u32(f2.z) | (f2bf_u32(f2.w) << 16);
            v1.z = f2bf_u32(f3.x) | (f2bf_u32(f3.y) << 16);
            v1.w = f2bf_u32(f3.z) | (f2bf_u32(f3.w) << 16);
            *(uint4v*)&As[ar * PADR + ac]     = v0;
            *(uint4v*)&As[ar * PADR + ac + 8] = v1;
        }
#pragma unroll
        for (int i = 0; i < 4; ++i) {
            const int kc = bk0 + i * 2;
            unsigned int s[8];
            if (!f32) {
                const u16* src = Wb16 + (size_t)(kk + kc * 8) * NW + bn;
#pragma unroll
                for (int j = 0; j < 8; ++j) s[j] = src[(size_t)j * NW];
            } else {
                const float* src = Wb32 + (size_t)(kk + kc * 8) * NW + bn;
#pragma unroll
                for (int j = 0; j < 8; ++j) s[j] = f2bf_u32(src[(size_t)j * NW]);
            }
            uint4v v;
            v.x = s[0] | (s[1] << 16);
            v.y = s[2] | (s[3] << 16);
            v.z = s[4] | (s[5] << 16);
            v.w = s[6] | (s[7] << 16);
            *(uint4v*)&Bs[bn * PADR + kc * 8] = v;
        }
        __syncthreads();
#pragma unroll
        for (int s = 0; s < 2; ++s) {
            bf16x8 a[2], bb[4];
#pragma unroll
            for (int im = 0; im < 2; ++im)
                a[im] = *(const bf16x8*)&As[(wm * 32 + im * 16 + l16) * PADR + s * 32 + q * 8];
#pragma unroll
            for (int in = 0; in < 4; ++in)
                bb[in] = *(const bf16x8*)&Bs[(wn * 64 + in * 16 + l16) * PADR + s * 32 + q * 8];
#pragma unroll
            for (int im = 0; im < 2; ++im)
#pragma unroll
                for (int in = 0; in < 4; ++in)
                    acc[im][in] = __builtin_amdgcn_mfma_f32_16x16x32_bf16(
                        a[im], bb[in], acc[im][in], 0, 0, 0);
        }
        __syncthreads();
    }

    const u16*   bias16 = (const u16*)BiasIn + (size_t)cat * NW + nt * TN;
    const float* bias32 = (const float*)BiasIn + (size_t)cat * NW + nt * TN;
    const size_t cOff = (size_t)b * TT * NW + (size_t)nt * TN;
    u16*   C16 = (u16*)Cout + cOff;
    float* C32 = (float*)Cout + cOff;
#pragma unroll
    for (int in = 0; in < 4; ++in) {
        const int ncol = wn * 64 + in * 16 + l16;
        const float bv = f32 ? bias32[ncol] : bf2f(bias16[ncol]);
#pragma unroll
        for (int im = 0; im < 2; ++im) {
#pragma unroll
            for (int r = 0; r < 4; ++r) {
                const int m = wm * 32 + im * 16 + q * 4 + r;
                float v = acc[im][in][r] + bv;
                if (RELU) v = fmaxf(v, 0.f);
                if (oF32) C32[(size_t)m * NW + ncol] = v;
                else      C16[(size_t)m * NW + ncol] = f2bf(v);
            }
        }
    }
}

extern "C" void kernel_launch(void* const* d_in, const int* in_sizes, int n_in,
                              void* d_out, int out_size, void* d_ws, size_t ws_size,
                              hipStream_t stream) {
    const void* x   = d_in[0];   // (128,64,1024)
    const void* W1  = d_in[1];   // (32,1024,1024)
    const void* b1  = d_in[2];   // (32,1024)
    const void* W2  = d_in[3];   // (32,1024,1536)
    const void* b2  = d_in[4];   // (32,1536)
    const int*  cid = (const int*)d_in[5];   // (128,) int32

    // ws layout: [h bf16 16MiB][W1T bf16 64MiB][W2T bf16 96MiB]
    const size_t hBytes   = (size_t)NB * TT * DHID * sizeof(u16);
    const size_t w1tBytes = (size_t)NCAT * KTOT * DHID * sizeof(u16);
    const size_t w2tBytes = (size_t)NCAT * KTOT * DOUT * sizeof(u16);
    u16* h = (u16*)d_ws;

    detect_dtype<<<1, 64, 0, stream>>>((const unsigned int*)x);

    if (ws_size >= hBytes + w1tBytes + w2tBytes) {
        u16* W1T = (u16*)((char*)d_ws + hBytes);
        u16* W2T = (u16*)((char*)d_ws + hBytes + w1tBytes);
        transpose_w<DHID><<<NCAT * 16 * (DHID / 256), 256, 0, stream>>>(W1, W1T);
        transpose_w<DOUT><<<NCAT * 16 * (DOUT / 256), 256, 0, stream>>>(W2, W2T);
        gemm_fast<DHID, true,  true,  false><<<NB * (DHID / TN), 256, 0, stream>>>(
            x, W1T, b1, (void*)h, cid);
        gemm_fast<DOUT, false, false, true ><<<NB * (DOUT / TN), 256, 0, stream>>>(
            (const void*)h, W2T, b2, d_out, cid);
    } else {
        gemm_cat_v2<DHID, true,  true,  false><<<NB * (DHID / TN), 256, 0, stream>>>(
            x, W1, b1, (void*)h, cid);
        gemm_cat_v2<DOUT, false, false, true ><<<NB * (DOUT / TN), 256, 0, stream>>>(
            (const void*)h, W2, b2, d_out, cid);
    }
}